// Round 3
// baseline (261.134 us; speedup 1.0000x reference)
//
#include <hip/hip_runtime.h>
#include <hip/hip_bf16.h>
#include <hip/hip_fp16.h>

#define BDIM    128   // batch size, fixed by problem
#define NGROUPS 4     // batch groups (32 batches each), one per XCD pair
#define GCOLS   32    // batch columns per group
#define EBLK    2048  // edge-kernel blocks (divisible by 8)
#define RANKS   (EBLK / NGROUPS)       // blocks per group = 512
#define S1BLK   (NGROUPS * 8)          // stage-1 reduce blocks
#define RPS     (RANKS / 8)            // ranks per stage-1 block = 64

#if __has_builtin(__builtin_nontemporal_load)
#define NT_LOAD(p) __builtin_nontemporal_load(p)
#else
#define NT_LOAD(p) (*(p))
#endif

// ---------------------------------------------------------------------------
// Kernel 1: transpose+convert x (B=128, N) f32 -> xTh[g][N][32] fp16 slices.
// Slice g holds batches [32g, 32g+32) so each slice is 3.2MB (L2-resident).
// ---------------------------------------------------------------------------
__global__ __launch_bounds__(256) void transpose_kernel(
    const float* __restrict__ x, __half* __restrict__ xTh, int N) {
  __shared__ float tile[64][BDIM + 1];
  const int tid = threadIdx.x;
  const int n0  = blockIdx.x * 64;

  // load: lane-within-64 walks n (coalesced), 4 b-rows at a time
  const int tn  = tid & 63;
  const int tb0 = tid >> 6;
  const int n   = n0 + tn;
  if (n < N) {
    for (int b = tb0; b < BDIM; b += 4)
      tile[tn][b] = x[(size_t)b * N + n];
  }
  __syncthreads();

  // store: thread = (k, g2, c2); per 16 lanes write 64B contiguous (16 half2)
  const int c2 = tid & 15;         // column pair within group
  const int g2 = (tid >> 4) & 3;   // group
  const int k  = tid >> 6;         // n sub-row 0..3
  for (int it = 0; it < 16; ++it) {
    const int nl = it * 4 + k;
    if (n0 + nl < N) {
      const float a = tile[nl][g2 * GCOLS + 2 * c2];
      const float b = tile[nl][g2 * GCOLS + 2 * c2 + 1];
      __half2* dst = (__half2*)(xTh + ((size_t)g2 * N + (n0 + nl)) * GCOLS + 2 * c2);
      *dst = __floats2half2_rn(a, b);
    }
  }
}

// ---------------------------------------------------------------------------
// Kernel 2: edge interactions, batch-split. Block -> (group, rank) via
// blockIdx%8 XCD affinity: group g = (blockIdx&7)>>1 lands on XCD pair
// {2g,2g+1}; its 3.2MB slice stays in those L2s. 16 lanes per edge, each
// lane owns one half2 (2 batches). Edge lists streamed nontemporal.
// ---------------------------------------------------------------------------
__global__ __launch_bounds__(256) void edge_kernel(
    const __half* __restrict__ xTh, const float* __restrict__ J,
    const int* __restrict__ ei, const int* __restrict__ ej,
    float* __restrict__ partials, int E, int N, int edges_per_rank) {
  const int tid  = threadIdx.x;
  const int g    = (blockIdx.x & 7) >> 1;
  const int rank = (blockIdx.x >> 3) * 2 + (blockIdx.x & 1);
  const __half* xg = xTh + (size_t)g * N * GCOLS;

  const int wave = tid >> 6;
  const int lane = tid & 63;
  const int k    = lane >> 4;   // edge sub-index 0..3
  const int c    = lane & 15;   // batch-pair 0..15

  const int start = rank * edges_per_rank;
  const int end   = min(start + edges_per_rank, E);

  float accx = 0.f, accy = 0.f;
  for (int e0 = start + wave * 4; e0 < end; e0 += 16) {
    const int e = e0 + k;
    if (e < end) {
      const int   i  = NT_LOAD(ei + e);
      const int   j  = NT_LOAD(ej + e);
      const float Jv = NT_LOAD(J + e);
      const __half2 xi = *(const __half2*)(xg + (size_t)i * GCOLS + 2 * c);
      const __half2 xj = *(const __half2*)(xg + (size_t)j * GCOLS + 2 * c);
      const float2 fi = __half22float2(xi);
      const float2 fj = __half22float2(xj);
      accx += (fi.x * fj.x) * Jv;
      accy += (fi.y * fj.y) * Jv;
    }
  }

  // combine the 4 k-lanes that share a batch-pair (xor 16, then 32)
  accx += __shfl_xor(accx, 16); accx += __shfl_xor(accx, 32);
  accy += __shfl_xor(accy, 16); accy += __shfl_xor(accy, 32);

  __shared__ float red[4][GCOLS];
  if (lane < 16) { red[wave][2 * c] = accx; red[wave][2 * c + 1] = accy; }
  __syncthreads();
  if (tid < GCOLS) {
    const float s = red[0][tid] + red[1][tid] + red[2][tid] + red[3][tid];
    partials[((size_t)g * RANKS + rank) * GCOLS + tid] = s;
  }
}

// ---------------------------------------------------------------------------
// Kernel 3: h-term directly from row-major x: block b sums x[b,:]*h[:].
// Coalesced row scan; deterministic fixed-order tree reduce.
// ---------------------------------------------------------------------------
__global__ __launch_bounds__(256) void h_kernel(
    const float* __restrict__ x, const float* __restrict__ h,
    float* __restrict__ h_out, int N) {
  const int b = blockIdx.x;
  const float* xr = x + (size_t)b * N;
  float acc = 0.f;
  for (int n = threadIdx.x; n < N; n += 256) acc += xr[n] * h[n];
  __shared__ float red[256];
  red[threadIdx.x] = acc;
  __syncthreads();
  for (int s = 128; s > 0; s >>= 1) {
    if (threadIdx.x < s) red[threadIdx.x] += red[threadIdx.x + s];
    __syncthreads();
  }
  if (threadIdx.x == 0) h_out[b] = red[0];
}

// ---------------------------------------------------------------------------
// Kernel 4a: stage-1 rank reduce: block (g,s) sums 64 rank rows -> 1 row.
// ---------------------------------------------------------------------------
__global__ __launch_bounds__(256) void reduce1_kernel(
    const float* __restrict__ P, float* __restrict__ P2) {
  const int g  = blockIdx.x >> 3;
  const int s  = blockIdx.x & 7;
  const int rl = threadIdx.x >> 5;  // 0..7
  const int c  = threadIdx.x & 31;
  float acc = 0.f;
  for (int rr = rl; rr < RPS; rr += 8)
    acc += P[((size_t)g * RANKS + s * RPS + rr) * GCOLS + c];
  __shared__ float red[8][GCOLS];
  red[rl][c] = acc;
  __syncthreads();
  if (threadIdx.x < GCOLS) {
    float sum = 0.f;
    for (int r = 0; r < 8; ++r) sum += red[r][threadIdx.x];
    P2[(size_t)blockIdx.x * GCOLS + threadIdx.x] = sum;
  }
}

// ---------------------------------------------------------------------------
// Kernel 4b: stage-2 final: out[b] = h_out[b] + sum_s P2[(g*8+s)][c].
// ---------------------------------------------------------------------------
__global__ __launch_bounds__(128) void reduce2_kernel(
    const float* __restrict__ P2, const float* __restrict__ h_out,
    float* __restrict__ out) {
  const int b = threadIdx.x;
  const int g = b >> 5;
  const int c = b & 31;
  float acc = h_out[b];
  for (int s = 0; s < 8; ++s)
    acc += P2[(size_t)(g * 8 + s) * GCOLS + c];
  out[b] = acc;
}

extern "C" void kernel_launch(void* const* d_in, const int* in_sizes, int n_in,
                              void* d_out, int out_size, void* d_ws, size_t ws_size,
                              hipStream_t stream) {
  const float* x  = (const float*)d_in[0];
  const float* h  = (const float*)d_in[1];
  const float* J  = (const float*)d_in[2];
  const int*   ei = (const int*)d_in[3];
  const int*   ej = (const int*)d_in[4];
  float* out = (float*)d_out;

  const int N = in_sizes[1];   // 50000
  const int E = in_sizes[2];   // 1600000

  // ws layout: xTh (4*N*32 halves = N*128*2B) | P (EBLK*32 f32) | P2 | h_out
  __half* xTh = (__half*)d_ws;
  float* P     = (float*)(xTh + (size_t)NGROUPS * N * GCOLS);
  float* P2    = P  + (size_t)EBLK * GCOLS;
  float* h_out = P2 + (size_t)S1BLK * GCOLS;

  // 1) transpose + fp16 convert into 4 batch-group slices
  const int tblocks = (N + 63) / 64;
  transpose_kernel<<<tblocks, 256, 0, stream>>>(x, xTh, N);

  // 2) h-term (independent of transpose)
  h_kernel<<<BDIM, 256, 0, stream>>>(x, h, h_out, N);

  // 3) edge interactions (4 batch groups, XCD-affine)
  const int epr = (E + RANKS - 1) / RANKS;
  edge_kernel<<<EBLK, 256, 0, stream>>>(xTh, J, ei, ej, P, E, N, epr);

  // 4) deterministic two-stage reduce (overwrites d_out)
  reduce1_kernel<<<S1BLK, 256, 0, stream>>>(P, P2);
  reduce2_kernel<<<1, BDIM, 0, stream>>>(P2, h_out, out);
}

// Round 4
// 133.417 us; speedup vs baseline: 1.9573x; 1.9573x over previous
//
#include <hip/hip_runtime.h>
#include <hip/hip_bf16.h>
#include <hip/hip_fp16.h>

#define BDIM    128   // batch size, fixed by problem
#define NGROUPS 4     // batch groups (32 batches each), one per XCD pair
#define GCOLS   32    // batch columns per group
#define ROWB    (GCOLS * 2)            // bytes per xTh row = 64
#define EBLK    2048  // edge-kernel blocks (divisible by 8)
#define RANKS   (EBLK / NGROUPS)       // blocks per group = 512
#define CHUNK   256   // edges staged in LDS per block iteration
#define S1BLK   (NGROUPS * 8)          // stage-1 reduce blocks
#define RPS     (RANKS / 8)            // ranks per stage-1 block = 64

// ---------------------------------------------------------------------------
// Kernel 1: transpose+convert x (B=128, N) f32 -> xTh[g][N][32] fp16 slices.
// Slice g holds batches [32g, 32g+32) so each slice is 3.2MB (L2-resident).
// ---------------------------------------------------------------------------
__global__ __launch_bounds__(256) void transpose_kernel(
    const float* __restrict__ x, __half* __restrict__ xTh, int N) {
  __shared__ float tile[64][BDIM + 1];
  const int tid = threadIdx.x;
  const int n0  = blockIdx.x * 64;

  // load: lane-within-64 walks n (coalesced), 4 b-rows at a time
  const int tn  = tid & 63;
  const int tb0 = tid >> 6;
  const int n   = n0 + tn;
  if (n < N) {
    for (int b = tb0; b < BDIM; b += 4)
      tile[tn][b] = x[(size_t)b * N + n];
  }
  __syncthreads();

  // store: thread = (k, g2, c2); per 16 lanes write 64B contiguous (16 half2)
  const int c2 = tid & 15;         // column pair within group
  const int g2 = (tid >> 4) & 3;   // group
  const int k  = tid >> 6;         // n sub-row 0..3
  for (int it = 0; it < 16; ++it) {
    const int nl = it * 4 + k;
    if (n0 + nl < N) {
      const float a = tile[nl][g2 * GCOLS + 2 * c2];
      const float b = tile[nl][g2 * GCOLS + 2 * c2 + 1];
      __half2* dst = (__half2*)(xTh + ((size_t)g2 * N + (n0 + nl)) * GCOLS + 2 * c2);
      *dst = __floats2half2_rn(a, b);
    }
  }
}

// ---------------------------------------------------------------------------
// Kernel 2: edge interactions, batch-split + LDS edge staging.
// Block -> (group, rank): group g=(blockIdx&7)>>1 lands on XCD pair {2g,2g+1}
// so its 3.2MB slice stays L2-resident. Per block iteration: 256 edges are
// staged into LDS (coalesced, software-pipelined via register prefetch),
// then 4 waves each process 64 of them, 4 edges per wave-step (16 lanes per
// edge, one half2 per lane). Tail padded with J=0 -> hot loop is branch-free.
// ---------------------------------------------------------------------------
__global__ __launch_bounds__(256) void edge_kernel(
    const __half* __restrict__ xTh, const float* __restrict__ J,
    const int* __restrict__ ei, const int* __restrict__ ej,
    float* __restrict__ partials, int E, int N, int edges_per_rank) {
  const int tid  = threadIdx.x;
  const int g    = (blockIdx.x & 7) >> 1;
  const int rank = (blockIdx.x >> 3) * 2 + (blockIdx.x & 1);
  const char* xgb = (const char*)(xTh + (size_t)g * N * GCOLS);

  const int wave = tid >> 6;
  const int lane = tid & 63;
  const int k    = lane >> 4;          // edge sub-index 0..3
  const int c4   = (lane & 15) * 4;    // byte offset of this lane's half2

  const int start = rank * edges_per_rank;
  const int end   = min(start + edges_per_rank, E);

  __shared__ int   si[CHUNK];
  __shared__ int   sj[CHUNK];
  __shared__ float sJ[CHUNK];

  // register prefetch of first chunk (T14: issue early, write late)
  int   ri = 0, rj = 0;
  float rJ = 0.f;
  {
    const int e = start + tid;
    if (e < end) { ri = ei[e]; rj = ej[e]; rJ = J[e]; }
  }

  float accx = 0.f, accy = 0.f;

  for (int base = start; base < end; base += CHUNK) {
    si[tid] = ri; sj[tid] = rj; sJ[tid] = rJ;
    __syncthreads();

    // issue next chunk's loads now; latency hides under the gather loop
    {
      const int e = base + CHUNK + tid;
      ri = 0; rj = 0; rJ = 0.f;
      if (e < end) { ri = ei[e]; rj = ej[e]; rJ = J[e]; }
    }

    const int lbase = wave * 64 + k;
#pragma unroll 4
    for (int u = 0; u < 16; ++u) {
      const int   l  = lbase + u * 4;
      const int   i  = si[l];
      const int   j  = sj[l];
      const float Jv = sJ[l];
      const __half2 xi = *(const __half2*)(xgb + (unsigned)i * ROWB + c4);
      const __half2 xj = *(const __half2*)(xgb + (unsigned)j * ROWB + c4);
      const float2 fi = __half22float2(xi);
      const float2 fj = __half22float2(xj);
      accx += (fi.x * fj.x) * Jv;
      accy += (fi.y * fj.y) * Jv;
    }
    __syncthreads();
  }

  // combine the 4 k-lanes that share a batch-pair (xor 16, then 32)
  accx += __shfl_xor(accx, 16); accx += __shfl_xor(accx, 32);
  accy += __shfl_xor(accy, 16); accy += __shfl_xor(accy, 32);

  __shared__ float red[4][GCOLS];
  if (lane < 16) { red[wave][2 * (lane & 15)] = accx;
                   red[wave][2 * (lane & 15) + 1] = accy; }
  __syncthreads();
  if (tid < GCOLS) {
    const float s = red[0][tid] + red[1][tid] + red[2][tid] + red[3][tid];
    partials[((size_t)g * RANKS + rank) * GCOLS + tid] = s;
  }
}

// ---------------------------------------------------------------------------
// Kernel 3: h-term directly from row-major x: block b sums x[b,:]*h[:].
// ---------------------------------------------------------------------------
__global__ __launch_bounds__(256) void h_kernel(
    const float* __restrict__ x, const float* __restrict__ h,
    float* __restrict__ h_out, int N) {
  const int b = blockIdx.x;
  const float* xr = x + (size_t)b * N;
  float acc = 0.f;
  for (int n = threadIdx.x; n < N; n += 256) acc += xr[n] * h[n];
  __shared__ float red[256];
  red[threadIdx.x] = acc;
  __syncthreads();
  for (int s = 128; s > 0; s >>= 1) {
    if (threadIdx.x < s) red[threadIdx.x] += red[threadIdx.x + s];
    __syncthreads();
  }
  if (threadIdx.x == 0) h_out[b] = red[0];
}

// ---------------------------------------------------------------------------
// Kernel 4a: stage-1 rank reduce: block (g,s) sums 64 rank rows -> 1 row.
// ---------------------------------------------------------------------------
__global__ __launch_bounds__(256) void reduce1_kernel(
    const float* __restrict__ P, float* __restrict__ P2) {
  const int g  = blockIdx.x >> 3;
  const int s  = blockIdx.x & 7;
  const int rl = threadIdx.x >> 5;  // 0..7
  const int c  = threadIdx.x & 31;
  float acc = 0.f;
  for (int rr = rl; rr < RPS; rr += 8)
    acc += P[((size_t)g * RANKS + s * RPS + rr) * GCOLS + c];
  __shared__ float red[8][GCOLS];
  red[rl][c] = acc;
  __syncthreads();
  if (threadIdx.x < GCOLS) {
    float sum = 0.f;
    for (int r = 0; r < 8; ++r) sum += red[r][threadIdx.x];
    P2[(size_t)blockIdx.x * GCOLS + threadIdx.x] = sum;
  }
}

// ---------------------------------------------------------------------------
// Kernel 4b: stage-2 final: out[b] = h_out[b] + sum_s P2[(g*8+s)][c].
// ---------------------------------------------------------------------------
__global__ __launch_bounds__(128) void reduce2_kernel(
    const float* __restrict__ P2, const float* __restrict__ h_out,
    float* __restrict__ out) {
  const int b = threadIdx.x;
  const int g = b >> 5;
  const int c = b & 31;
  float acc = h_out[b];
  for (int s = 0; s < 8; ++s)
    acc += P2[(size_t)(g * 8 + s) * GCOLS + c];
  out[b] = acc;
}

extern "C" void kernel_launch(void* const* d_in, const int* in_sizes, int n_in,
                              void* d_out, int out_size, void* d_ws, size_t ws_size,
                              hipStream_t stream) {
  const float* x  = (const float*)d_in[0];
  const float* h  = (const float*)d_in[1];
  const float* J  = (const float*)d_in[2];
  const int*   ei = (const int*)d_in[3];
  const int*   ej = (const int*)d_in[4];
  float* out = (float*)d_out;

  const int N = in_sizes[1];   // 50000
  const int E = in_sizes[2];   // 1600000

  // ws layout: xTh (4*N*32 halves) | P (EBLK*32 f32) | P2 (S1BLK*32) | h_out (128)
  __half* xTh = (__half*)d_ws;
  float* P     = (float*)(xTh + (size_t)NGROUPS * N * GCOLS);
  float* P2    = P  + (size_t)EBLK * GCOLS;
  float* h_out = P2 + (size_t)S1BLK * GCOLS;

  // 1) transpose + fp16 convert into 4 batch-group slices
  const int tblocks = (N + 63) / 64;
  transpose_kernel<<<tblocks, 256, 0, stream>>>(x, xTh, N);

  // 2) h-term (independent of transpose)
  h_kernel<<<BDIM, 256, 0, stream>>>(x, h, h_out, N);

  // 3) edge interactions (4 batch groups, XCD-affine, LDS edge staging)
  const int epr = (E + RANKS - 1) / RANKS;
  edge_kernel<<<EBLK, 256, 0, stream>>>(xTh, J, ei, ej, P, E, N, epr);

  // 4) deterministic two-stage reduce (overwrites d_out)
  reduce1_kernel<<<S1BLK, 256, 0, stream>>>(P, P2);
  reduce2_kernel<<<1, BDIM, 0, stream>>>(P2, h_out, out);
}

// Round 5
// 91.914 us; speedup vs baseline: 2.8411x; 1.4515x over previous
//
#include <hip/hip_runtime.h>
#include <hip/hip_bf16.h>
#include <hip/hip_fp16.h>

#define BDIM    128   // batch size, fixed by problem
#define NGROUPS 4     // batch groups (32 batches each), one per XCD pair
#define GCOLS   32    // batch columns per group
#define ROWB    (GCOLS * 2)            // bytes per xTh row = 64
#define EBLK    2048  // edge-kernel blocks (divisible by 8)
#define RANKS   (EBLK / NGROUPS)       // blocks per group = 512
#define CHUNK   256   // edges staged in LDS per block iteration
#define S1BLK   (NGROUPS * 8)          // stage-1 edge-reduce blocks = 32
#define HBLK2   8     // stage-1 h-reduce blocks
#define RPS     (RANKS / 8)            // ranks per stage-1 block = 64

// ---------------------------------------------------------------------------
// Kernel 1: transpose+convert x (B=128,N) f32 -> xTh[g][N][32] fp16 slices,
// FUSED with h-term partials: hp[block][b] = sum_{n in tile} x[b,n]*h[n].
// Slice g holds batches [32g,32g+32) -> 3.2MB, L2-resident per XCD pair.
// ---------------------------------------------------------------------------
__global__ __launch_bounds__(256) void transpose_h_kernel(
    const float* __restrict__ x, const float* __restrict__ h,
    __half* __restrict__ xTh, float* __restrict__ hp, int N) {
  __shared__ float tile[64][BDIM + 1];
  __shared__ float sh[64];
  __shared__ float red2[2][BDIM];
  const int tid = threadIdx.x;
  const int n0  = blockIdx.x * 64;

  // load: lane-within-64 walks n (coalesced), 4 b-rows at a time
  const int tn  = tid & 63;
  const int tb0 = tid >> 6;
  const int n   = n0 + tn;
  if (n < N) {
    for (int b = tb0; b < BDIM; b += 4) tile[tn][b] = x[(size_t)b * N + n];
  } else {
    for (int b = tb0; b < BDIM; b += 4) tile[tn][b] = 0.f;
  }
  if (tid < 64) sh[tid] = (n0 + tid < N) ? h[n0 + tid] : 0.f;
  __syncthreads();

  // h-term partial: thread (half, b) sums 32 n's (tile reads stride-1: no conflict)
  const int hb   = tid & 127;
  const int half = tid >> 7;
  float hacc = 0.f;
#pragma unroll
  for (int m = 0; m < 32; ++m) {
    const int nl = half * 32 + m;
    hacc += tile[nl][hb] * sh[nl];
  }
  red2[half][hb] = hacc;

  // transpose store: thread = (k, g2, c2); 16 lanes write 64B contiguous
  const int c2 = tid & 15;         // column pair within group
  const int g2 = (tid >> 4) & 3;   // group
  const int k  = tid >> 6;         // n sub-row 0..3
  for (int it = 0; it < 16; ++it) {
    const int nl = it * 4 + k;
    if (n0 + nl < N) {
      const float a = tile[nl][g2 * GCOLS + 2 * c2];
      const float b = tile[nl][g2 * GCOLS + 2 * c2 + 1];
      __half2* dst = (__half2*)(xTh + ((size_t)g2 * N + (n0 + nl)) * GCOLS + 2 * c2);
      *dst = __floats2half2_rn(a, b);
    }
  }
  __syncthreads();
  if (tid < BDIM) hp[(size_t)blockIdx.x * BDIM + tid] = red2[0][tid] + red2[1][tid];
}

// ---------------------------------------------------------------------------
// Kernel 2: edge interactions. 4 lanes per edge, each lane gathers 16B
// (8 fp16 columns) -> 16 edges per wave-step. Edge (i,j) packed as int2 in
// LDS (one b64 read), J one b32. Packed __hmul2 products, f32 accumulate.
// Block -> (group, rank): group g=(blockIdx&7)>>1 -> XCD pair {2g,2g+1},
// 3.2MB slice stays L2-resident. Tail padded with J=0 -> branch-free loop.
// ---------------------------------------------------------------------------
__global__ __launch_bounds__(256) void edge_kernel(
    const __half* __restrict__ xTh, const float* __restrict__ J,
    const int* __restrict__ ei, const int* __restrict__ ej,
    float* __restrict__ partials, int E, int N, int edges_per_rank) {
  const int tid  = threadIdx.x;
  const int g    = (blockIdx.x & 7) >> 1;
  const int rank = (blockIdx.x >> 3) * 2 + (blockIdx.x & 1);
  const char* xgl = (const char*)(xTh + (size_t)g * N * GCOLS) + (tid & 3) * 16;

  const int wave = tid >> 6;
  const int lane = tid & 63;
  const int k    = lane >> 2;          // edge sub-index 0..15
  const int q    = lane & 3;           // column quarter 0..3

  const int start = rank * edges_per_rank;
  const int end   = min(start + edges_per_rank, E);

  __shared__ int2  sij[CHUNK];
  __shared__ float sJ[CHUNK];

  // register prefetch of first chunk (issue early, write late)
  int ri = 0, rj = 0;
  float rJ = 0.f;
  {
    const int e = start + tid;
    if (e < end) { ri = ei[e]; rj = ej[e]; rJ = J[e]; }
  }

  float acc[8] = {0.f, 0.f, 0.f, 0.f, 0.f, 0.f, 0.f, 0.f};

  for (int base = start; base < end; base += CHUNK) {
    sij[tid] = make_int2(ri, rj);
    sJ[tid]  = rJ;
    __syncthreads();

    // issue next chunk's loads; latency hides under the gather loop
    {
      const int e = base + CHUNK + tid;
      ri = 0; rj = 0; rJ = 0.f;
      if (e < end) { ri = ei[e]; rj = ej[e]; rJ = J[e]; }
    }

    const int lbase = wave * 64 + k;
#pragma unroll
    for (int u = 0; u < 4; ++u) {
      const int   l  = lbase + u * 16;
      const int2  ij = sij[l];
      const float Jv = sJ[l];
      const int4 vi = *(const int4*)(xgl + (unsigned)ij.x * ROWB);
      const int4 vj = *(const int4*)(xgl + (unsigned)ij.y * ROWB);
      const int wi[4] = {vi.x, vi.y, vi.z, vi.w};
      const int wj[4] = {vj.x, vj.y, vj.z, vj.w};
#pragma unroll
      for (int w = 0; w < 4; ++w) {
        const __half2 hi = __builtin_bit_cast(__half2, wi[w]);
        const __half2 hj = __builtin_bit_cast(__half2, wj[w]);
        const __half2 p  = __hmul2(hi, hj);
        acc[2 * w]     += __low2float(p)  * Jv;
        acc[2 * w + 1] += __high2float(p) * Jv;
      }
    }
    __syncthreads();
  }

  // combine the 16 k-lanes sharing each column quarter (xor 4,8,16,32)
#pragma unroll
  for (int off = 4; off < 64; off <<= 1)
#pragma unroll
    for (int w = 0; w < 8; ++w) acc[w] += __shfl_xor(acc[w], off);

  __shared__ float red[4][GCOLS];
  if (lane < 4)
#pragma unroll
    for (int w = 0; w < 8; ++w) red[wave][q * 8 + w] = acc[w];
  __syncthreads();
  if (tid < GCOLS) {
    const float s = red[0][tid] + red[1][tid] + red[2][tid] + red[3][tid];
    partials[((size_t)g * RANKS + rank) * GCOLS + tid] = s;
  }
}

// ---------------------------------------------------------------------------
// Kernel 3: stage-1 reduce. Blocks [0,32): edge partials (g,s) sum 64 rank
// rows -> P2. Blocks [32,40): h partials, block s sums rows r%8==s -> hp2.
// ---------------------------------------------------------------------------
__global__ __launch_bounds__(256) void reduce1_kernel(
    const float* __restrict__ P, const float* __restrict__ hp,
    float* __restrict__ P2, float* __restrict__ hp2, int hrows) {
  __shared__ float red[8][GCOLS];
  __shared__ float redh[2][BDIM];
  if (blockIdx.x < S1BLK) {
    const int g  = blockIdx.x >> 3;
    const int s  = blockIdx.x & 7;
    const int rl = threadIdx.x >> 5;  // 0..7
    const int c  = threadIdx.x & 31;
    float acc = 0.f;
    for (int rr = rl; rr < RPS; rr += 8)
      acc += P[((size_t)g * RANKS + s * RPS + rr) * GCOLS + c];
    red[rl][c] = acc;
    __syncthreads();
    if (threadIdx.x < GCOLS) {
      float sum = 0.f;
      for (int r = 0; r < 8; ++r) sum += red[r][threadIdx.x];
      P2[(size_t)blockIdx.x * GCOLS + threadIdx.x] = sum;
    }
  } else {
    const int s  = blockIdx.x - S1BLK;   // 0..7
    const int b  = threadIdx.x & 127;
    const int rg = threadIdx.x >> 7;
    float acc = 0.f;
    for (int r = s + 8 * rg; r < hrows; r += 16)
      acc += hp[(size_t)r * BDIM + b];
    redh[rg][b] = acc;
    __syncthreads();
    if (threadIdx.x < BDIM)
      hp2[(size_t)s * BDIM + threadIdx.x] = redh[0][threadIdx.x] + redh[1][threadIdx.x];
  }
}

// ---------------------------------------------------------------------------
// Kernel 4: final: out[b] = sum_s hp2[s][b] + sum_s P2[(g*8+s)][c].
// ---------------------------------------------------------------------------
__global__ __launch_bounds__(128) void reduce2_kernel(
    const float* __restrict__ P2, const float* __restrict__ hp2,
    float* __restrict__ out) {
  const int b = threadIdx.x;
  const int g = b >> 5;
  const int c = b & 31;
  float acc = 0.f;
  for (int s = 0; s < 8; ++s) acc += hp2[(size_t)s * BDIM + b];
  for (int s = 0; s < 8; ++s) acc += P2[(size_t)(g * 8 + s) * GCOLS + c];
  out[b] = acc;
}

extern "C" void kernel_launch(void* const* d_in, const int* in_sizes, int n_in,
                              void* d_out, int out_size, void* d_ws, size_t ws_size,
                              hipStream_t stream) {
  const float* x  = (const float*)d_in[0];
  const float* h  = (const float*)d_in[1];
  const float* J  = (const float*)d_in[2];
  const int*   ei = (const int*)d_in[3];
  const int*   ej = (const int*)d_in[4];
  float* out = (float*)d_out;

  const int N = in_sizes[1];   // 50000
  const int E = in_sizes[2];   // 1600000

  const int tblocks = (N + 63) / 64;

  // ws layout: xTh (4*N*32 halves) | P (EBLK*32) | P2 (32*32) | hp (tblocks*128) | hp2 (8*128)
  __half* xTh = (__half*)d_ws;
  float* P   = (float*)(xTh + (size_t)NGROUPS * N * GCOLS);
  float* P2  = P   + (size_t)EBLK * GCOLS;
  float* hp  = P2  + (size_t)S1BLK * GCOLS;
  float* hp2 = hp  + (size_t)tblocks * BDIM;

  // 1) transpose + fp16 convert + h-term partials
  transpose_h_kernel<<<tblocks, 256, 0, stream>>>(x, h, xTh, hp, N);

  // 2) edge interactions (4 batch groups, XCD-affine, 16B gathers)
  const int epr = (E + RANKS - 1) / RANKS;
  edge_kernel<<<EBLK, 256, 0, stream>>>(xTh, J, ei, ej, P, E, N, epr);

  // 3) stage-1 reduce (edge partials + h partials)
  reduce1_kernel<<<S1BLK + HBLK2, 256, 0, stream>>>(P, hp, P2, hp2, tblocks);

  // 4) final deterministic reduce (overwrites d_out)
  reduce2_kernel<<<1, BDIM, 0, stream>>>(P2, hp2, out);
}